// Round 2
// baseline (1163.951 us; speedup 1.0000x reference)
//
#include <hip/hip_runtime.h>

#define NN   12288
#define FIN  256
#define FOUT 128
#define ALPHA 0.2f

typedef __attribute__((ext_vector_type(8))) _Float16 half8v;
typedef __attribute__((ext_vector_type(4))) float float4v;
typedef __attribute__((ext_vector_type(4))) int   int4v;

// ---------------------------------------------------------------------------
// Kernel 1: Wh = h @ W  (fp32).
//   - writes WhT[FOUT][NN] as f16 (transposed, for MFMA B-fragment loads)
//   - writes Wh1[i] = Wh[i]·a[0:128], Wh2[i] = Wh[i]·a[128:256] (fp32)
// One block = 16 rows of h, 128 threads (thread t owns output column t).
// ---------------------------------------------------------------------------
__global__ __launch_bounds__(128) void k_wh(
    const float* __restrict__ h,
    const float* __restrict__ W,
    const float* __restrict__ a,
    _Float16* __restrict__ WhT,
    float* __restrict__ Wh1, float* __restrict__ Wh2)
{
    __shared__ __align__(16) float hs[16 * FIN];   // 16 KB
    __shared__ float sP1[2][16], sP2[2][16];
    const int t = threadIdx.x;                     // 0..127
    const int row0 = blockIdx.x * 16;

    // stage h[row0..row0+16][:] (4096 contiguous floats = 1024 float4)
    const float4v* hsrc = (const float4v*)(h + (size_t)row0 * FIN);
    float4v* hdst = (float4v*)hs;
    #pragma unroll
    for (int i = 0; i < 8; ++i) hdst[t + i * 128] = hsrc[t + i * 128];
    __syncthreads();

    float acc[16];
    #pragma unroll
    for (int r = 0; r < 16; ++r) acc[r] = 0.f;

    for (int k = 0; k < FIN; k += 4) {
        const float w0 = W[(k + 0) * FOUT + t];
        const float w1 = W[(k + 1) * FOUT + t];
        const float w2 = W[(k + 2) * FOUT + t];
        const float w3 = W[(k + 3) * FOUT + t];
        #pragma unroll
        for (int r = 0; r < 16; ++r) {
            const float4v hv = *(const float4v*)&hs[r * FIN + k];
            float s = acc[r];
            s = fmaf(hv.x, w0, s);
            s = fmaf(hv.y, w1, s);
            s = fmaf(hv.z, w2, s);
            s = fmaf(hv.w, w3, s);
            acc[r] = s;
        }
    }

    // WhT[t][row0..row0+16] as f16 (32B contiguous per thread)
    half8v pk0, pk1;
    #pragma unroll
    for (int r = 0; r < 8; ++r)  pk0[r] = (_Float16)acc[r];
    #pragma unroll
    for (int r = 0; r < 8; ++r)  pk1[r] = (_Float16)acc[8 + r];
    half8v* dst = (half8v*)(WhT + (size_t)t * NN + row0);
    dst[0] = pk0;
    dst[1] = pk1;

    // Wh1/Wh2 reductions across the 128 threads (feature dim)
    const float a1t = a[t];
    const float a2t = a[FOUT + t];
    const int lane = t & 63, wv = t >> 6;
    #pragma unroll
    for (int r = 0; r < 16; ++r) {
        float v1 = acc[r] * a1t;
        float v2 = acc[r] * a2t;
        #pragma unroll
        for (int off = 1; off < 64; off <<= 1) {
            v1 += __shfl_xor(v1, off, 64);
            v2 += __shfl_xor(v2, off, 64);
        }
        if (lane == 0) { sP1[wv][r] = v1; sP2[wv][r] = v2; }
    }
    __syncthreads();
    if (t < 16) {
        Wh1[row0 + t] = sP1[0][t] + sP1[1][t];
        Wh2[row0 + t] = sP2[0][t] + sP2[1][t];
    }
}

// ---------------------------------------------------------------------------
// Kernel 1b: maxWh2 = max_j Wh2[j]
// ---------------------------------------------------------------------------
__global__ __launch_bounds__(256) void k_max(
    const float* __restrict__ Wh2, float* __restrict__ outmax)
{
    __shared__ float sm[4];
    float m = -1e30f;
    for (int i = threadIdx.x; i < NN; i += 256) m = fmaxf(m, Wh2[i]);
    #pragma unroll
    for (int off = 1; off < 64; off <<= 1) m = fmaxf(m, __shfl_xor(m, off, 64));
    if ((threadIdx.x & 63) == 0) sm[threadIdx.x >> 6] = m;
    __syncthreads();
    if (threadIdx.x == 0)
        outmax[0] = fmaxf(fmaxf(sm[0], sm[1]), fmaxf(sm[2], sm[3]));
}

// ---------------------------------------------------------------------------
// Kernel 2: fused masked-softmax attention + PV GEMM + ELU.
// One wave per 16 output rows. Lane owns A-row m=lane&15, k-quad q=lane>>4.
// P is computed directly in MFMA A-fragment layout (A[m][k=q*8+j]) — no LDS.
// Mi = leaky(Wh1_i + max_j Wh2_j) >= row max score  =>  exp(e-Mi) <= 1,
// single pass, no online rescale. Softmax is shift-invariant (same Mi in
// numerator and denominator). Denominator sums the f16-rounded numerators so
// weights sum to exactly 1.
// ---------------------------------------------------------------------------
__global__ __launch_bounds__(64) void k_attn(
    const int* __restrict__ adj,
    const _Float16* __restrict__ WhT,
    const float* __restrict__ Wh1, const float* __restrict__ Wh2,
    const float* __restrict__ maxp,
    float* __restrict__ out)
{
    const int lane = threadIdx.x;
    const int m = lane & 15;
    const int q = lane >> 4;
    const int i = blockIdx.x * 16 + m;

    const float wh1 = Wh1[i];
    const float tm = wh1 + maxp[0];
    const float Mi = fmaxf(tm, ALPHA * tm);

    float4v c[8];
    #pragma unroll
    for (int t = 0; t < 8; ++t) c[t] = (float4v){0.f, 0.f, 0.f, 0.f};
    float S = 0.f;

    const int* adjrow = adj + (size_t)i * NN;

    for (int j0 = 0; j0 < NN; j0 += 32) {
        const int jb = j0 + q * 8;
        const int4v  a0  = *(const int4v*)(adjrow + jb);
        const int4v  a1  = *(const int4v*)(adjrow + jb + 4);
        const float4v w0 = *(const float4v*)(Wh2 + jb);
        const float4v w1 = *(const float4v*)(Wh2 + jb + 4);

        half8v bfr[8];
        #pragma unroll
        for (int t = 0; t < 8; ++t)
            bfr[t] = *(const half8v*)(WhT + (size_t)(t * 16 + m) * NN + jb);

        float pv[8];
        {
            float e;
            e = wh1 + w0.x; e = fmaxf(e, ALPHA * e); pv[0] = (a0.x != 0) ? __expf(e - Mi) : 0.f;
            e = wh1 + w0.y; e = fmaxf(e, ALPHA * e); pv[1] = (a0.y != 0) ? __expf(e - Mi) : 0.f;
            e = wh1 + w0.z; e = fmaxf(e, ALPHA * e); pv[2] = (a0.z != 0) ? __expf(e - Mi) : 0.f;
            e = wh1 + w0.w; e = fmaxf(e, ALPHA * e); pv[3] = (a0.w != 0) ? __expf(e - Mi) : 0.f;
            e = wh1 + w1.x; e = fmaxf(e, ALPHA * e); pv[4] = (a1.x != 0) ? __expf(e - Mi) : 0.f;
            e = wh1 + w1.y; e = fmaxf(e, ALPHA * e); pv[5] = (a1.y != 0) ? __expf(e - Mi) : 0.f;
            e = wh1 + w1.z; e = fmaxf(e, ALPHA * e); pv[6] = (a1.z != 0) ? __expf(e - Mi) : 0.f;
            e = wh1 + w1.w; e = fmaxf(e, ALPHA * e); pv[7] = (a1.w != 0) ? __expf(e - Mi) : 0.f;
        }

        half8v af;
        #pragma unroll
        for (int jj = 0; jj < 8; ++jj) {
            const _Float16 p = (_Float16)pv[jj];
            af[jj] = p;
            S += (float)p;          // denominator consistent with f16 numerator
        }

        #pragma unroll
        for (int t = 0; t < 8; ++t)
            c[t] = __builtin_amdgcn_mfma_f32_16x16x32_f16(af, bfr[t], c[t], 0, 0, 0);
    }

    // combine the 4 k-quad partials of S per row (lanes m, m+16, m+32, m+48)
    S += __shfl_xor(S, 16, 64);
    S += __shfl_xor(S, 32, 64);

    // epilogue: D row = q*4+reg (output row), col = m (feature within t-block)
    #pragma unroll
    for (int reg = 0; reg < 4; ++reg) {
        const int mloc = q * 4 + reg;
        const float Sr = __shfl(S, mloc, 64);
        const float inv = 1.f / fmaxf(Sr, 1e-30f);
        const int irow = blockIdx.x * 16 + mloc;
        #pragma unroll
        for (int t = 0; t < 8; ++t) {
            float v = c[t][reg] * inv;
            float o = (v > 0.f) ? v : (__expf(v) - 1.f);
            out[(size_t)irow * FOUT + t * 16 + m] = o;
        }
    }
}

// ---------------------------------------------------------------------------
extern "C" void kernel_launch(void* const* d_in, const int* in_sizes, int n_in,
                              void* d_out, int out_size, void* d_ws, size_t ws_size,
                              hipStream_t stream) {
    const float* h   = (const float*)d_in[0];
    const int*   adj = (const int*)d_in[1];
    const float* W   = (const float*)d_in[2];
    const float* a   = (const float*)d_in[3];
    float* out = (float*)d_out;

    char* ws = (char*)d_ws;
    float* Wh1 = (float*)ws;                         // 49152 B
    float* Wh2 = (float*)(ws + 49152);               // 49152 B
    float* mx  = (float*)(ws + 98304);               // 256 B
    _Float16* WhT = (_Float16*)(ws + 98560);         // 128*12288*2 B

    k_wh  <<<NN / 16, 128, 0, stream>>>(h, W, a, WhT, Wh1, Wh2);
    k_max <<<1, 256, 0, stream>>>(Wh2, mx);
    k_attn<<<NN / 16, 64, 0, stream>>>(adj, WhT, Wh1, Wh2, mx, out);
}

// Round 3
// 1119.340 us; speedup vs baseline: 1.0399x; 1.0399x over previous
//
#include <hip/hip_runtime.h>

#define NN   12288
#define FIN  256
#define FOUT 128
#define ALPHA 0.2f

typedef __attribute__((ext_vector_type(8))) _Float16 half8v;
typedef __attribute__((ext_vector_type(4))) float float4v;
typedef __attribute__((ext_vector_type(4))) int   int4v;

// ---------------------------------------------------------------------------
// Kernel 1: Wh = h @ W  (fp32).
//   - writes WhT[FOUT][NN] as f16 (transposed, for MFMA B-fragment loads)
//   - writes Wh1[i] = Wh[i]·a[0:128], Wh2[i] = Wh[i]·a[128:256] (fp32)
// One block = 16 rows of h, 128 threads (thread t owns output column t).
// ---------------------------------------------------------------------------
__global__ __launch_bounds__(128) void k_wh(
    const float* __restrict__ h,
    const float* __restrict__ W,
    const float* __restrict__ a,
    _Float16* __restrict__ WhT,
    float* __restrict__ Wh1, float* __restrict__ Wh2)
{
    __shared__ __align__(16) float hs[16 * FIN];   // 16 KB
    __shared__ float sP1[2][16], sP2[2][16];
    const int t = threadIdx.x;                     // 0..127
    const int row0 = blockIdx.x * 16;

    // stage h[row0..row0+16][:] (4096 contiguous floats = 1024 float4)
    const float4v* hsrc = (const float4v*)(h + (size_t)row0 * FIN);
    float4v* hdst = (float4v*)hs;
    #pragma unroll
    for (int i = 0; i < 8; ++i) hdst[t + i * 128] = hsrc[t + i * 128];
    __syncthreads();

    float acc[16];
    #pragma unroll
    for (int r = 0; r < 16; ++r) acc[r] = 0.f;

    for (int k = 0; k < FIN; k += 4) {
        const float w0 = W[(k + 0) * FOUT + t];
        const float w1 = W[(k + 1) * FOUT + t];
        const float w2 = W[(k + 2) * FOUT + t];
        const float w3 = W[(k + 3) * FOUT + t];
        #pragma unroll
        for (int r = 0; r < 16; ++r) {
            const float4v hv = *(const float4v*)&hs[r * FIN + k];
            float s = acc[r];
            s = fmaf(hv.x, w0, s);
            s = fmaf(hv.y, w1, s);
            s = fmaf(hv.z, w2, s);
            s = fmaf(hv.w, w3, s);
            acc[r] = s;
        }
    }

    // WhT[t][row0..row0+16] as f16 (32B contiguous per thread)
    half8v pk0, pk1;
    #pragma unroll
    for (int r = 0; r < 8; ++r)  pk0[r] = (_Float16)acc[r];
    #pragma unroll
    for (int r = 0; r < 8; ++r)  pk1[r] = (_Float16)acc[8 + r];
    half8v* dst = (half8v*)(WhT + (size_t)t * NN + row0);
    dst[0] = pk0;
    dst[1] = pk1;

    // Wh1/Wh2 reductions across the 128 threads (feature dim)
    const float a1t = a[t];
    const float a2t = a[FOUT + t];
    const int lane = t & 63, wv = t >> 6;
    #pragma unroll
    for (int r = 0; r < 16; ++r) {
        float v1 = acc[r] * a1t;
        float v2 = acc[r] * a2t;
        #pragma unroll
        for (int off = 1; off < 64; off <<= 1) {
            v1 += __shfl_xor(v1, off, 64);
            v2 += __shfl_xor(v2, off, 64);
        }
        if (lane == 0) { sP1[wv][r] = v1; sP2[wv][r] = v2; }
    }
    __syncthreads();
    if (t < 16) {
        Wh1[row0 + t] = sP1[0][t] + sP1[1][t];
        Wh2[row0 + t] = sP2[0][t] + sP2[1][t];
    }
}

// ---------------------------------------------------------------------------
// Kernel 1b: maxWh2 = max_j Wh2[j]
// ---------------------------------------------------------------------------
__global__ __launch_bounds__(256) void k_max(
    const float* __restrict__ Wh2, float* __restrict__ outmax)
{
    __shared__ float sm[4];
    float m = -1e30f;
    for (int i = threadIdx.x; i < NN; i += 256) m = fmaxf(m, Wh2[i]);
    #pragma unroll
    for (int off = 1; off < 64; off <<= 1) m = fmaxf(m, __shfl_xor(m, off, 64));
    if ((threadIdx.x & 63) == 0) sm[threadIdx.x >> 6] = m;
    __syncthreads();
    if (threadIdx.x == 0)
        outmax[0] = fmaxf(fmaxf(sm[0], sm[1]), fmaxf(sm[2], sm[3]));
}

// ---------------------------------------------------------------------------
// Kernel 2: fused masked-softmax attention + PV GEMM + ELU.
// 256 threads = 4 waves per block; wave w processes j in [w*3072, (w+1)*3072).
// Within a wave: lane owns A-row m=lane&15, k-quad q=lane>>4; P is computed
// directly in MFMA A-fragment layout (A[m][k=q*8+j]) — no LDS round-trip.
// Mi = leaky(Wh1_i + max_j Wh2_j) >= row max score => exp(e-Mi) <= 1: single
// pass, no online rescale (softmax is shift-invariant; same Mi in num+den).
// Partial C (8 x float4) and S combined across the 4 waves via LDS; wave w
// writes output columns [32w, 32w+32).
// ---------------------------------------------------------------------------
__global__ __launch_bounds__(256) void k_attn(
    const int* __restrict__ adj,
    const _Float16* __restrict__ WhT,
    const float* __restrict__ Wh1, const float* __restrict__ Wh2,
    const float* __restrict__ maxp,
    float* __restrict__ out)
{
    __shared__ __align__(16) float cbuf[4][8][64][4];   // 32 KB: [wave][t][lane][reg]
    __shared__ float sbuf[4][16];                       // per-wave row sums
    const int tid  = threadIdx.x;
    const int w    = tid >> 6;
    const int lane = tid & 63;
    const int m    = lane & 15;
    const int q    = lane >> 4;
    const int i    = blockIdx.x * 16 + m;

    const float wh1 = Wh1[i];
    const float tm = wh1 + maxp[0];
    const float Mi = fmaxf(tm, ALPHA * tm);

    float4v c[8];
    #pragma unroll
    for (int t = 0; t < 8; ++t) c[t] = (float4v){0.f, 0.f, 0.f, 0.f};
    float S = 0.f;

    const int* adjrow = adj + (size_t)i * NN;
    const int jbeg = w * (NN / 4);
    const int jend = jbeg + (NN / 4);

    for (int j0 = jbeg; j0 < jend; j0 += 32) {
        const int jb = j0 + q * 8;
        const int4v  a0  = *(const int4v*)(adjrow + jb);
        const int4v  a1  = *(const int4v*)(adjrow + jb + 4);
        const float4v w0 = *(const float4v*)(Wh2 + jb);
        const float4v w1 = *(const float4v*)(Wh2 + jb + 4);

        half8v bfr[8];
        #pragma unroll
        for (int t = 0; t < 8; ++t)
            bfr[t] = *(const half8v*)(WhT + (size_t)(t * 16 + m) * NN + jb);

        float pv[8];
        {
            float e;
            e = wh1 + w0.x; e = fmaxf(e, ALPHA * e); pv[0] = (a0.x != 0) ? __expf(e - Mi) : 0.f;
            e = wh1 + w0.y; e = fmaxf(e, ALPHA * e); pv[1] = (a0.y != 0) ? __expf(e - Mi) : 0.f;
            e = wh1 + w0.z; e = fmaxf(e, ALPHA * e); pv[2] = (a0.z != 0) ? __expf(e - Mi) : 0.f;
            e = wh1 + w0.w; e = fmaxf(e, ALPHA * e); pv[3] = (a0.w != 0) ? __expf(e - Mi) : 0.f;
            e = wh1 + w1.x; e = fmaxf(e, ALPHA * e); pv[4] = (a1.x != 0) ? __expf(e - Mi) : 0.f;
            e = wh1 + w1.y; e = fmaxf(e, ALPHA * e); pv[5] = (a1.y != 0) ? __expf(e - Mi) : 0.f;
            e = wh1 + w1.z; e = fmaxf(e, ALPHA * e); pv[6] = (a1.z != 0) ? __expf(e - Mi) : 0.f;
            e = wh1 + w1.w; e = fmaxf(e, ALPHA * e); pv[7] = (a1.w != 0) ? __expf(e - Mi) : 0.f;
        }

        half8v af;
        #pragma unroll
        for (int jj = 0; jj < 8; ++jj) {
            const _Float16 p = (_Float16)pv[jj];
            af[jj] = p;
            S += (float)p;          // denominator consistent with f16 numerator
        }

        #pragma unroll
        for (int t = 0; t < 8; ++t)
            c[t] = __builtin_amdgcn_mfma_f32_16x16x32_f16(af, bfr[t], c[t], 0, 0, 0);
    }

    // intra-wave: combine the 4 k-quad partials of S per row
    S += __shfl_xor(S, 16, 64);
    S += __shfl_xor(S, 32, 64);
    if (lane < 16) sbuf[w][lane] = S;

    #pragma unroll
    for (int t = 0; t < 8; ++t)
        *(float4v*)&cbuf[w][t][lane][0] = c[t];
    __syncthreads();

    // cross-wave combine + epilogue: wave w handles t in {2w, 2w+1}
    #pragma unroll
    for (int tt = 0; tt < 2; ++tt) {
        const int t = w * 2 + tt;
        float4v cs = *(const float4v*)&cbuf[0][t][lane][0];
        #pragma unroll
        for (int w2 = 1; w2 < 4; ++w2) {
            const float4v o = *(const float4v*)&cbuf[w2][t][lane][0];
            cs.x += o.x; cs.y += o.y; cs.z += o.z; cs.w += o.w;
        }
        #pragma unroll
        for (int reg = 0; reg < 4; ++reg) {
            const int mloc = q * 4 + reg;
            const float Sr = sbuf[0][mloc] + sbuf[1][mloc] + sbuf[2][mloc] + sbuf[3][mloc];
            const float inv = 1.f / fmaxf(Sr, 1e-30f);
            const float v = cs[reg] * inv;
            const float o = (v > 0.f) ? v : (__expf(v) - 1.f);
            out[(size_t)(blockIdx.x * 16 + mloc) * FOUT + t * 16 + m] = o;
        }
    }
}

// ---------------------------------------------------------------------------
extern "C" void kernel_launch(void* const* d_in, const int* in_sizes, int n_in,
                              void* d_out, int out_size, void* d_ws, size_t ws_size,
                              hipStream_t stream) {
    const float* h   = (const float*)d_in[0];
    const int*   adj = (const int*)d_in[1];
    const float* W   = (const float*)d_in[2];
    const float* a   = (const float*)d_in[3];
    float* out = (float*)d_out;

    char* ws = (char*)d_ws;
    float* Wh1 = (float*)ws;                         // 49152 B
    float* Wh2 = (float*)(ws + 49152);               // 49152 B
    float* mx  = (float*)(ws + 98304);               // 256 B
    _Float16* WhT = (_Float16*)(ws + 98560);         // 128*12288*2 B

    k_wh  <<<NN / 16, 128, 0, stream>>>(h, W, a, WhT, Wh1, Wh2);
    k_max <<<1, 256, 0, stream>>>(Wh2, mx);
    k_attn<<<NN / 16, 256, 0, stream>>>(adj, WhT, Wh1, Wh2, mx, out);
}